// Round 11
// baseline (431.757 us; speedup 1.0000x reference)
//
#include <hip/hip_runtime.h>
#include <cstdint>
#include <cstddef>

#define NBATCH 128
#define NCH    256
#define NHW    1024
#define NTIME  64
#define NCLS   128

typedef _Float16 half2_t __attribute__((ext_vector_type(2)));
typedef short bf16x8 __attribute__((ext_vector_type(8)));
typedef short bf16x4 __attribute__((ext_vector_type(4)));
typedef float f32x4 __attribute__((ext_vector_type(4)));
typedef unsigned short ushort_t;

#if defined(__has_builtin)
#  if __has_builtin(__builtin_amdgcn_fdot2)
#    define HAS_FDOT2 1
#  endif
#endif
#ifndef HAS_FDOT2
#  define HAS_FDOT2 0
#endif

__device__ __forceinline__ float dot2acc(half2_t a, half2_t b, float c){
#if HAS_FDOT2
  return __builtin_amdgcn_fdot2(a, b, c, false);
#else
  return c + (float)a.x*(float)b.x + (float)a.y*(float)b.y;
#endif
}
__device__ __forceinline__ half2_t pack2(float x, float y){
  half2_t p; p.x = (_Float16)x; p.y = (_Float16)y; return p;
}
#define BCH(x) __builtin_bit_cast(half2_t, (x))
__device__ __forceinline__ ushort_t f2bf(float x){
  unsigned u = __builtin_bit_cast(unsigned, x);
  unsigned r = (u + 0x7FFFu + ((u>>16)&1u)) >> 16;
  return (ushort_t)r;
}
__device__ __forceinline__ float sig_(float x){
  x = fminf(30.f, fmaxf(-30.f, x));
  return 1.f/(1.f+__expf(-x));
}
__device__ __forceinline__ float tanh_(float x){
  x = fminf(15.f, fmaxf(-15.f, x));
  float e = __expf(2.f*x);
  return (e-1.f)/(e+1.f);
}

// ---------------- K0: row sums of A -> S[b*64+t] ----------------
__global__ __launch_bounds__(256) void k_rowsum(const float* __restrict__ A, float* __restrict__ S){
  int row = blockIdx.x;
  const float4* a4 = (const float4*)(A + (size_t)row*NHW);
  float4 v = a4[threadIdx.x];
  float s = v.x+v.y+v.z+v.w;
  #pragma unroll
  for (int off=32; off>0; off>>=1) s += __shfl_down(s, off, 64);
  __shared__ float wsum[4];
  int lane = threadIdx.x & 63, w = threadIdx.x >> 6;
  if (lane==0) wsum[w] = s;
  __syncthreads();
  if (threadIdx.x==0) S[row] = wsum[0]+wsum[1]+wsum[2]+wsum[3];
}

// ---------------- weight fp32 -> bf16 convert ----------------
__global__ __launch_bounds__(256) void k_convw(const float* __restrict__ src, ushort_t* __restrict__ dst, int n){
  int i = blockIdx.x*256 + threadIdx.x;
  if (i < n) dst[i] = f2bf(src[i]);
}

// ---------------- K1: attention pooling via MFMA ----------------
__global__ __launch_bounds__(256) void k_pool_mfma(const float* __restrict__ feat, const float* __restrict__ A,
    const float* __restrict__ S, ushort_t* __restrict__ Cbf){
  __shared__ ushort_t As_[64*40];
  __shared__ ushort_t Fs_[128*40];
  __shared__ float sinvs[64];
  int b = blockIdx.x >> 1, ch = blockIdx.x & 1, c0 = ch*128;
  int tid = threadIdx.x, wave = tid>>6, lane = tid&63;
  if (tid < 64) sinvs[tid] = 1.f / S[b*64 + tid];
  f32x4 acc[4][2] = {};
  int lr = lane & 15, lk = (lane>>4)*8;
  for (int k0=0;k0<NHW;k0+=32){
    __syncthreads();
    #pragma unroll
    for (int i=0;i<2;i++){
      int c = tid + i*256, r = c>>3, kq = c&7;
      float4 v = *(const float4*)(A + ((size_t)(b*64+r))*NHW + k0 + kq*4);
      bf16x4 p; p[0]=(short)f2bf(v.x); p[1]=(short)f2bf(v.y); p[2]=(short)f2bf(v.z); p[3]=(short)f2bf(v.w);
      *(bf16x4*)&As_[r*40 + kq*4] = p;
    }
    #pragma unroll
    for (int i=0;i<4;i++){
      int c = tid + i*256, r = c>>3, kq = c&7;
      float4 v = *(const float4*)(feat + ((size_t)(b*256+c0+r))*NHW + k0 + kq*4);
      bf16x4 p; p[0]=(short)f2bf(v.x); p[1]=(short)f2bf(v.y); p[2]=(short)f2bf(v.z); p[3]=(short)f2bf(v.w);
      *(bf16x4*)&Fs_[r*40 + kq*4] = p;
    }
    __syncthreads();
    bf16x8 af[4], bg[2];
    #pragma unroll
    for (int m=0;m<4;m++) af[m] = *(const bf16x8*)&As_[(m*16 + lr)*40 + lk];
    #pragma unroll
    for (int n=0;n<2;n++) bg[n] = *(const bf16x8*)&Fs_[(wave*32 + n*16 + lr)*40 + lk];
    #pragma unroll
    for (int m=0;m<4;m++)
      #pragma unroll
      for (int n=0;n<2;n++)
        acc[m][n] = __builtin_amdgcn_mfma_f32_16x16x32_bf16(af[m], bg[n], acc[m][n], 0, 0, 0);
  }
  #pragma unroll
  for (int m=0;m<4;m++)
    #pragma unroll
    for (int n=0;n<2;n++)
      #pragma unroll
      for (int j=0;j<4;j++){
        int t = m*16 + (lane>>4)*4 + j;
        int c = c0 + wave*32 + n*16 + lr;
        Cbf[((size_t)t*NBATCH + b)*NCH + c] = f2bf(acc[m][n][j] * sinvs[t]);
      }
}

// ---------------- generic bf16 MFMA GEMM: out[M][N]fp32 = Xbf[M][K] @ Wbf[N][K]^T + ba(+bb) ---
__global__ __launch_bounds__(256) void k_gemm_bf(const ushort_t* __restrict__ X, const ushort_t* __restrict__ W,
    const float* __restrict__ ba, const float* __restrict__ bb, float* __restrict__ out, int N, int K){
  __shared__ ushort_t Xs[128*40];
  __shared__ ushort_t Ws[128*40];
  int n0 = blockIdx.x*128, m0 = blockIdx.y*128;
  int tid = threadIdx.x, wave = tid>>6, lane = tid&63;
  int wr = wave>>1, wc = wave&1;
  int lr = lane & 15, lk = (lane>>4)*8;
  f32x4 acc[4][4] = {};
  for (int k0=0;k0<K;k0+=32){
    __syncthreads();
    #pragma unroll
    for (int i=0;i<2;i++){
      int c = tid + i*256, r = c>>2, kb = c&3;
      *(bf16x8*)&Xs[r*40 + kb*8] = *(const bf16x8*)(X + (size_t)(m0+r)*K + k0 + kb*8);
      *(bf16x8*)&Ws[r*40 + kb*8] = *(const bf16x8*)(W + (size_t)(n0+r)*K + k0 + kb*8);
    }
    __syncthreads();
    bf16x8 af[4], bg[4];
    #pragma unroll
    for (int m=0;m<4;m++) af[m] = *(const bf16x8*)&Xs[(wr*64 + m*16 + lr)*40 + lk];
    #pragma unroll
    for (int n=0;n<4;n++) bg[n] = *(const bf16x8*)&Ws[(wc*64 + n*16 + lr)*40 + lk];
    #pragma unroll
    for (int m=0;m<4;m++)
      #pragma unroll
      for (int n=0;n<4;n++)
        acc[m][n] = __builtin_amdgcn_mfma_f32_16x16x32_bf16(af[m], bg[n], acc[m][n], 0, 0, 0);
  }
  float bsv[4];
  #pragma unroll
  for (int n=0;n<4;n++){
    int col = n0 + wc*64 + n*16 + lr;
    bsv[n] = ba[col] + (bb ? bb[col] : 0.f);
  }
  #pragma unroll
  for (int m=0;m<4;m++)
    #pragma unroll
    for (int n=0;n<4;n++)
      #pragma unroll
      for (int j=0;j<4;j++){
        int row = m0 + wr*64 + m*16 + (lane>>4)*4 + j;
        int col = n0 + wc*64 + n*16 + lr;
        out[(size_t)row*N + col] = acc[m][n][j] + bsv[n];
      }
}

// ---------------- K7: packed normalized attention output ----------------
__global__ __launch_bounds__(256) void k_attns(const float* __restrict__ A, const float* __restrict__ S,
    const int* __restrict__ pack_b, const int* __restrict__ pack_t, float* __restrict__ outA){
  int i = blockIdx.x;
  int b = pack_b[i], t = pack_t[i];
  float is = 1.f / S[b*64 + t];
  float4 v = ((const float4*)(A + ((size_t)(b*64+t))*NHW))[threadIdx.x];
  v.x*=is; v.y*=is; v.z*=is; v.w*=is;
  ((float4*)(outA + (size_t)i*NHW))[threadIdx.x] = v;
}

// ==== named-register weight machinery (no arrays -> no alloca -> no scratch) ====
#define LWP(j,p0,p1) { float4 v = wr[j]; W##p0 = pack2(v.x,v.y); W##p1 = pack2(v.z,v.w); }

// ---------------- K3: BiLSTM scan, 64 NAMED weight regs ----------------
// 256 blocks = 128 samples x 2 dirs, 512 threads = 512 gate rows, K=128.
__global__ __launch_bounds__(512, 2) void k_lstm(const float* __restrict__ Gf, const float* __restrict__ Gb,
    const float* __restrict__ Whh_f, const float* __restrict__ Whh_b, ushort_t* __restrict__ Clbf){
  int b = blockIdx.x & 127, dir = blockIdx.x >> 7;
  int g = threadIdx.x, lane = g & 63;
  const float* Whh = dir ? Whh_b : Whh_f;
  const float* G   = dir ? Gb    : Gf;
  half2_t W0,W1,W2,W3,W4,W5,W6,W7,W8,W9,W10,W11,W12,W13,W14,W15,
          W16,W17,W18,W19,W20,W21,W22,W23,W24,W25,W26,W27,W28,W29,W30,W31,
          W32,W33,W34,W35,W36,W37,W38,W39,W40,W41,W42,W43,W44,W45,W46,W47,
          W48,W49,W50,W51,W52,W53,W54,W55,W56,W57,W58,W59,W60,W61,W62,W63;
  {
    const float4* wr = (const float4*)(Whh + (size_t)g*128);
    LWP(0,0,1)   LWP(1,2,3)   LWP(2,4,5)   LWP(3,6,7)
    LWP(4,8,9)   LWP(5,10,11) LWP(6,12,13) LWP(7,14,15)
    LWP(8,16,17) LWP(9,18,19) LWP(10,20,21) LWP(11,22,23)
    LWP(12,24,25) LWP(13,26,27) LWP(14,28,29) LWP(15,30,31)
    LWP(16,32,33) LWP(17,34,35) LWP(18,36,37) LWP(19,38,39)
    LWP(20,40,41) LWP(21,42,43) LWP(22,44,45) LWP(23,46,47)
    LWP(24,48,49) LWP(25,50,51) LWP(26,52,53) LWP(27,54,55)
    LWP(28,56,57) LWP(29,58,59) LWP(30,60,61) LWP(31,62,63)
  }
  __shared__ float h32[128];
  __shared__ float gates[512];
  if (g < 128) h32[g] = 0.f;
  float c = 0.f;
  __syncthreads();
  #pragma unroll 1
  for (int t=0;t<NTIME;t++){
    int tt = dir ? (NTIME-1-t) : t;
    float gv = G[((size_t)tt*NBATCH + b)*512 + g];
    float2 hp2 = *(const float2*)(h32 + 2*lane);
    int hpk = __builtin_bit_cast(int, pack2(hp2.x, hp2.y));
    float A0=0.f, A1=0.f, A2=0.f, A3=0.f;
#define DL(p,ACC) ACC = dot2acc(W##p, BCH(__builtin_amdgcn_readlane(hpk,p)), ACC);
#define DL4(p0,p1,p2,p3) DL(p0,A0) DL(p1,A1) DL(p2,A2) DL(p3,A3)
    DL4(0,1,2,3)     DL4(4,5,6,7)     DL4(8,9,10,11)   DL4(12,13,14,15)
    DL4(16,17,18,19) DL4(20,21,22,23) DL4(24,25,26,27) DL4(28,29,30,31)
    DL4(32,33,34,35) DL4(36,37,38,39) DL4(40,41,42,43) DL4(44,45,46,47)
    DL4(48,49,50,51) DL4(52,53,54,55) DL4(56,57,58,59) DL4(60,61,62,63)
#undef DL4
#undef DL
    gates[g] = gv + A0+A1+A2+A3;
    __syncthreads();
    if (g < 128){
      float gi=gates[g], gf=gates[128+g], gg=gates[256+g], go=gates[384+g];
      c = sig_(gf)*c + sig_(gi)*tanh_(gg);
      float h = sig_(go)*tanh_(c);
      h32[g] = h;
      Clbf[((size_t)tt*NBATCH + b)*NCH + dir*128 + g] = f2bf(h);
    }
    __syncthreads();
  }
}

// ---------------- K4a: xs(bf16) = [Cl_bf | emb->bf16] ----------------
__global__ __launch_bounds__(256) void k_xs(const ushort_t* __restrict__ Clbf, const float* __restrict__ emb,
    const int* __restrict__ text, ushort_t* __restrict__ xsbf){
  int idx = blockIdx.x*256 + threadIdx.x;       // 8-elem chunks: 8192 rows x 64
  int row = idx>>6, c8 = idx&63;
  int t = row>>7, b = row&127;
  bf16x8 v;
  if (c8 < 32) v = *(const bf16x8*)(Clbf + (size_t)row*NCH + c8*8);
  else {
    int cls = (t==0) ? 0 : text[b*64 + (t-1)];
    const float4* e4 = (const float4*)(emb + (size_t)cls*NCH + (c8-32)*8);
    float4 a = e4[0], bq = e4[1];
    v[0]=(short)f2bf(a.x);  v[1]=(short)f2bf(a.y);  v[2]=(short)f2bf(a.z);  v[3]=(short)f2bf(a.w);
    v[4]=(short)f2bf(bq.x); v[5]=(short)f2bf(bq.y); v[6]=(short)f2bf(bq.z); v[7]=(short)f2bf(bq.w);
  }
  *(bf16x8*)(xsbf + (size_t)row*512 + c8*8) = v;
}

// ---------------- K5: GRU scan, 768 threads = 768 rows, 128 NAMED weight regs ----------------
// R2-proven shape: thread g owns full row g (K=256 -> 128 half2). h pair p: lane p>>1,
// reg p&1 (hpk0 even / hpk1 odd).
__global__ __launch_bounds__(768, 3) void k_gru(const float* __restrict__ gx,
    const float* __restrict__ Whh_g, const float* __restrict__ bhh_g, ushort_t* __restrict__ hsbf){
  int b = blockIdx.x, g = threadIdx.x, lane = g & 63;
  half2_t W0,W1,W2,W3,W4,W5,W6,W7,W8,W9,W10,W11,W12,W13,W14,W15,
          W16,W17,W18,W19,W20,W21,W22,W23,W24,W25,W26,W27,W28,W29,W30,W31,
          W32,W33,W34,W35,W36,W37,W38,W39,W40,W41,W42,W43,W44,W45,W46,W47,
          W48,W49,W50,W51,W52,W53,W54,W55,W56,W57,W58,W59,W60,W61,W62,W63,
          W64,W65,W66,W67,W68,W69,W70,W71,W72,W73,W74,W75,W76,W77,W78,W79,
          W80,W81,W82,W83,W84,W85,W86,W87,W88,W89,W90,W91,W92,W93,W94,W95,
          W96,W97,W98,W99,W100,W101,W102,W103,W104,W105,W106,W107,W108,W109,W110,W111,
          W112,W113,W114,W115,W116,W117,W118,W119,W120,W121,W122,W123,W124,W125,W126,W127;
  {
    const float4* wr = (const float4*)(Whh_g + (size_t)g*256);
    LWP(0,0,1)     LWP(1,2,3)     LWP(2,4,5)     LWP(3,6,7)
    LWP(4,8,9)     LWP(5,10,11)   LWP(6,12,13)   LWP(7,14,15)
    LWP(8,16,17)   LWP(9,18,19)   LWP(10,20,21)  LWP(11,22,23)
    LWP(12,24,25)  LWP(13,26,27)  LWP(14,28,29)  LWP(15,30,31)
    LWP(16,32,33)  LWP(17,34,35)  LWP(18,36,37)  LWP(19,38,39)
    LWP(20,40,41)  LWP(21,42,43)  LWP(22,44,45)  LWP(23,46,47)
    LWP(24,48,49)  LWP(25,50,51)  LWP(26,52,53)  LWP(27,54,55)
    LWP(28,56,57)  LWP(29,58,59)  LWP(30,60,61)  LWP(31,62,63)
    LWP(32,64,65)  LWP(33,66,67)  LWP(34,68,69)  LWP(35,70,71)
    LWP(36,72,73)  LWP(37,74,75)  LWP(38,76,77)  LWP(39,78,79)
    LWP(40,80,81)  LWP(41,82,83)  LWP(42,84,85)  LWP(43,86,87)
    LWP(44,88,89)  LWP(45,90,91)  LWP(46,92,93)  LWP(47,94,95)
    LWP(48,96,97)  LWP(49,98,99)  LWP(50,100,101) LWP(51,102,103)
    LWP(52,104,105) LWP(53,106,107) LWP(54,108,109) LWP(55,110,111)
    LWP(56,112,113) LWP(57,114,115) LWP(58,116,117) LWP(59,118,119)
    LWP(60,120,121) LWP(61,122,123) LWP(62,124,125) LWP(63,126,127)
  }
  float bh = bhh_g[g];
  __shared__ float h32[256];
  __shared__ float ghs[768];
  if (g < 256) h32[g] = 0.f;
  float hprev = 0.f;
  __syncthreads();
  #pragma unroll 1
  for (int t=0;t<NTIME;t++){
    float gxr=0.f, gxz=0.f, gxn=0.f;
    if (g < 256){
      const float* gxp = gx + ((size_t)t*NBATCH + b)*768;
      gxr = gxp[g]; gxz = gxp[256+g]; gxn = gxp[512+g];
    }
    // lane l holds h[4l..4l+3]: hpk0=(h[4l],h[4l+1]) (even pairs), hpk1=(h[4l+2],h[4l+3]) (odd)
    float4 hq = *(const float4*)(h32 + 4*lane);
    int hpk0 = __builtin_bit_cast(int, pack2(hq.x, hq.y));
    int hpk1 = __builtin_bit_cast(int, pack2(hq.z, hq.w));
    float A0=0.f, A1=0.f, A2=0.f, A3=0.f;
#define DG(p,SRC,ACC) ACC = dot2acc(W##p, BCH(__builtin_amdgcn_readlane(SRC,(p)>>1)), ACC);
#define DG4(p0,p1,p2,p3) DG(p0,hpk0,A0) DG(p1,hpk1,A1) DG(p2,hpk0,A2) DG(p3,hpk1,A3)
    DG4(0,1,2,3)         DG4(4,5,6,7)         DG4(8,9,10,11)       DG4(12,13,14,15)
    DG4(16,17,18,19)     DG4(20,21,22,23)     DG4(24,25,26,27)     DG4(28,29,30,31)
    DG4(32,33,34,35)     DG4(36,37,38,39)     DG4(40,41,42,43)     DG4(44,45,46,47)
    DG4(48,49,50,51)     DG4(52,53,54,55)     DG4(56,57,58,59)     DG4(60,61,62,63)
    DG4(64,65,66,67)     DG4(68,69,70,71)     DG4(72,73,74,75)     DG4(76,77,78,79)
    DG4(80,81,82,83)     DG4(84,85,86,87)     DG4(88,89,90,91)     DG4(92,93,94,95)
    DG4(96,97,98,99)     DG4(100,101,102,103) DG4(104,105,106,107) DG4(108,109,110,111)
    DG4(112,113,114,115) DG4(116,117,118,119) DG4(120,121,122,123) DG4(124,125,126,127)
#undef DG4
#undef DG
    ghs[g] = bh + A0+A1+A2+A3;
    __syncthreads();
    if (g < 256){
      float r = sig_(gxr + ghs[g]);
      float z = sig_(gxz + ghs[256+g]);
      float n = tanh_(gxn + r*ghs[512+g]);
      float h = (1.f-z)*n + z*hprev;
      hprev = h;
      h32[g] = h;
      hsbf[((size_t)t*NBATCH + b)*NCH + g] = f2bf(h);
    }
    __syncthreads();
  }
}

// ---------------- K6: logits via MFMA with row gather ----------------
__global__ __launch_bounds__(256) void k_logits_mfma(const ushort_t* __restrict__ hsbf,
    const int* __restrict__ pack_t, const int* __restrict__ pack_b,
    const ushort_t* __restrict__ Wbf, const float* __restrict__ bias,
    float* __restrict__ out, int L){
  __shared__ ushort_t Xs[64*40];
  __shared__ ushort_t Ws[128*40];
  __shared__ int rrow[64];
  int m0 = blockIdx.x*64;
  int tid = threadIdx.x, wave = tid>>6, lane = tid&63;
  int lr = lane & 15, lk = (lane>>4)*8;
  if (tid < 64){
    int m = m0 + tid;
    int pt = (m<L) ? pack_t[m] : 0;
    int pb = (m<L) ? pack_b[m] : 0;
    rrow[tid] = pt*NBATCH + pb;
  }
  f32x4 acc[4][2] = {};
  for (int k0=0;k0<NCH;k0+=32){
    __syncthreads();
    {
      int r = tid>>2, kb = tid&3;
      *(bf16x8*)&Xs[r*40 + kb*8] = *(const bf16x8*)(hsbf + (size_t)rrow[r]*NCH + k0 + kb*8);
    }
    #pragma unroll
    for (int i=0;i<2;i++){
      int c = tid + i*256, r = c>>2, kb = c&3;
      *(bf16x8*)&Ws[r*40 + kb*8] = *(const bf16x8*)(Wbf + (size_t)r*NCH + k0 + kb*8);
    }
    __syncthreads();
    bf16x8 af[4], bg[2];
    #pragma unroll
    for (int m=0;m<4;m++) af[m] = *(const bf16x8*)&Xs[(m*16 + lr)*40 + lk];
    #pragma unroll
    for (int n=0;n<2;n++) bg[n] = *(const bf16x8*)&Ws[(wave*32 + n*16 + lr)*40 + lk];
    #pragma unroll
    for (int m=0;m<4;m++)
      #pragma unroll
      for (int n=0;n<2;n++)
        acc[m][n] = __builtin_amdgcn_mfma_f32_16x16x32_bf16(af[m], bg[n], acc[m][n], 0, 0, 0);
  }
  #pragma unroll
  for (int m=0;m<4;m++)
    #pragma unroll
    for (int n=0;n<2;n++)
      #pragma unroll
      for (int j=0;j<4;j++){
        int row = m0 + m*16 + (lane>>4)*4 + j;
        int col = wave*32 + n*16 + lr;
        if (row < L) out[(size_t)row*NCLS + col] = acc[m][n][j] + bias[col];
      }
}

extern "C" void kernel_launch(void* const* d_in, const int* in_sizes, int n_in,
                              void* d_out, int out_size, void* d_ws, size_t ws_size,
                              hipStream_t stream) {
  const float* feature = (const float*)d_in[0];
  const float* A       = (const float*)d_in[1];
  const int*   text    = (const int*)d_in[2];
  const int*   pack_b  = (const int*)d_in[4];
  const int*   pack_t  = (const int*)d_in[5];
  const float* emb     = (const float*)d_in[6];
  const float* Wih_f   = (const float*)d_in[7];
  const float* Whh_f   = (const float*)d_in[8];
  const float* bih_f   = (const float*)d_in[9];
  const float* bhh_f   = (const float*)d_in[10];
  const float* Wih_b   = (const float*)d_in[11];
  const float* Whh_b   = (const float*)d_in[12];
  const float* bih_b   = (const float*)d_in[13];
  const float* bhh_b   = (const float*)d_in[14];
  const float* Wih_g   = (const float*)d_in[15];
  const float* Whh_g   = (const float*)d_in[16];
  const float* bih_g   = (const float*)d_in[17];
  const float* bhh_g   = (const float*)d_in[18];
  const float* Wgen    = (const float*)d_in[19];
  const float* bgen    = (const float*)d_in[20];
  int L = in_sizes[4];

  char* ws = (char*)d_ws;
  const size_t MB = 1u<<20;
  float*    S       = (float*)(ws + 0);                    // 32 KB
  ushort_t* Wf_bf   = (ushort_t*)(ws + 1*MB);              // 256 KB
  ushort_t* Wb_bf   = (ushort_t*)(ws + 1*MB + 256*1024);   // 256 KB
  ushort_t* Wg_bf   = (ushort_t*)(ws + 1*MB + 512*1024);   // 768 KB
  ushort_t* Wgen_bf = (ushort_t*)(ws + 1*MB + 1280*1024);  // 64 KB
  ushort_t* Cbf     = (ushort_t*)(ws + 3*MB);              // 4 MB  [t][b][256]
  ushort_t* Clbf    = (ushort_t*)(ws + 7*MB);              // 4 MB
  ushort_t* hsbf    = (ushort_t*)(ws + 11*MB);             // 4 MB
  float*    Gf      = (float*)(ws + 16*MB);                // 16 MB (dead after k_lstm)
  float*    Gb      = (float*)(ws + 32*MB);                // 16 MB (dead after k_lstm)
  ushort_t* xsbf    = (ushort_t*)(ws + 16*MB);             // 8 MB, aliases Gf
  float*    gx      = (float*)(ws + 24*MB);                // 25.2 MB, aliases Gb+

  float* out_res   = (float*)d_out;
  float* out_attns = out_res + (size_t)L*NCLS;

  k_convw<<<512, 256, 0, stream>>>(Wih_f, Wf_bf, 512*256);
  k_convw<<<512, 256, 0, stream>>>(Wih_b, Wb_bf, 512*256);
  k_convw<<<1536, 256, 0, stream>>>(Wih_g, Wg_bf, 768*512);
  k_convw<<<128, 256, 0, stream>>>(Wgen, Wgen_bf, 128*256);
  k_rowsum<<<8192, 256, 0, stream>>>(A, S);
  k_pool_mfma<<<256, 256, 0, stream>>>(feature, A, S, Cbf);
  k_attns<<<L, 256, 0, stream>>>(A, S, pack_b, pack_t, out_attns);
  k_gemm_bf<<<dim3(4,64), 256, 0, stream>>>(Cbf, Wf_bf, bih_f, bhh_f, Gf, 512, 256);
  k_gemm_bf<<<dim3(4,64), 256, 0, stream>>>(Cbf, Wb_bf, bih_b, bhh_b, Gb, 512, 256);
  k_lstm<<<256, 512, 0, stream>>>(Gf, Gb, Whh_f, Whh_b, Clbf);
  k_xs<<<2048, 256, 0, stream>>>(Clbf, emb, text, xsbf);
  k_gemm_bf<<<dim3(6,64), 256, 0, stream>>>(xsbf, Wg_bf, bih_g, nullptr, gx, 768, 512);
  k_gru<<<128, 768, 0, stream>>>(gx, Whh_g, bhh_g, hsbf);
  k_logits_mfma<<<(L+63)/64, 256, 0, stream>>>(hsbf, pack_t, pack_b, Wgen_bf, bgen, out_res, L);
}